// Round 6
// baseline (349.820 us; speedup 1.0000x reference)
//
#include <hip/hip_runtime.h>
#include <stdint.h>

typedef float f32x4 __attribute__((ext_vector_type(4)));
typedef float f32x2 __attribute__((ext_vector_type(2)));

#define LOG2E 1.4426950408889634f

__device__ __forceinline__ float rcp_f(float x) { return __builtin_amdgcn_rcpf(x); }
__device__ __forceinline__ float sqrt_f(float x) { return __builtin_amdgcn_sqrtf(x); }
__device__ __forceinline__ float exp2_f(float x) { return __builtin_amdgcn_exp2f(x); }
__device__ __forceinline__ float tanh_fast(float a) {
    float e = exp2_f(a * (2.0f * LOG2E));
    return 1.0f - 2.0f * rcp_f(e + 1.0f);
}

__device__ __forceinline__ f32x2 sp(float s) { return (f32x2){s, s}; }
__device__ __forceinline__ f32x2 fma2(f32x2 a, f32x2 b, f32x2 c) {
    return __builtin_elementwise_fma(a, b, c);
}
__device__ __forceinline__ f32x2 max2(f32x2 a, f32x2 b) {
    return __builtin_elementwise_max(a, b);
}
__device__ __forceinline__ f32x2 rcp2(f32x2 a)  { return (f32x2){rcp_f(a.x),  rcp_f(a.y)};  }
__device__ __forceinline__ f32x2 sqrt2(f32x2 a) { return (f32x2){sqrt_f(a.x), sqrt_f(a.y)}; }
__device__ __forceinline__ f32x2 exp22(f32x2 a) { return (f32x2){exp2_f(a.x), exp2_f(a.y)}; }

struct Params {
    float we0, we1, be, wd0, wd1, bd0, bd1;
    float w1[30], b1[10], w2[20], b20, b21;
};

// Scalar path (tail blocks only) — identical op sequence to the packed path.
__device__ __forceinline__ void compute_row(const Params& p, float x0, float x1, float o[8]) {
    float enc = fmaf(x1, p.we1, fmaf(x0, p.we0, p.be));
    float d0  = fmaf(enc, p.wd0, p.bd0);
    float d1  = fmaf(enc, p.wd1, p.bd1);
    float xn  = sqrt_f(fmaf(x1, x1, x0 * x0));
    float dn  = sqrt_f(fmaf(d1, d1, d0 * d0));
    float dot = fmaf(x1, d1, x0 * d0);
    float cosv = dot * rcp_f(fmaxf(xn, 1e-8f) * fmaxf(dn, 1e-8f));
    float e0 = x0 - d0, e1 = x1 - d1;
    float eu = sqrt_f(fmaf(e1, e1, e0 * e0)) * rcp_f(xn);
    float l0 = p.b20, l1 = p.b21;
#pragma unroll
    for (int j = 0; j < 10; ++j) {
        float a = fmaf(enc, p.w1[3*j],
                  fmaf(eu,  p.w1[3*j+1],
                  fmaf(cosv, p.w1[3*j+2], p.b1[j])));
        float h = tanh_fast(a);
        l0 = fmaf(h, p.w2[j],      l0);
        l1 = fmaf(h, p.w2[10 + j], l1);
    }
    float m  = fmaxf(l0, l1);
    float q0 = exp2_f((l0 - m) * LOG2E);
    float q1 = exp2_f((l1 - m) * LOG2E);
    float inv = rcp_f(q0 + q1);
    o[0] = enc; o[1] = d0; o[2] = d1;
    o[3] = enc; o[4] = eu; o[5] = cosv;
    o[6] = q0 * inv; o[7] = q1 * inv;
}

struct PairOut { f32x2 enc, d0, d1, eu, cosv, g0, g1; };

// Two rows at once (v_pk_* for non-trans ops). Per-lane op order == compute_row.
// Called separately inside each segment branch so unused tail DCEs per segment.
__device__ __forceinline__ PairOut compute_pair(const Params& p, f32x2 x0, f32x2 x1) {
    PairOut r;
    f32x2 enc = fma2(x1, sp(p.we1), fma2(x0, sp(p.we0), sp(p.be)));
    f32x2 d0  = fma2(enc, sp(p.wd0), sp(p.bd0));
    f32x2 d1  = fma2(enc, sp(p.wd1), sp(p.bd1));
    f32x2 xn  = sqrt2(fma2(x1, x1, x0 * x0));
    f32x2 dn  = sqrt2(fma2(d1, d1, d0 * d0));
    f32x2 dot = fma2(x1, d1, x0 * d0);
    f32x2 cosv = dot * rcp2(max2(xn, sp(1e-8f)) * max2(dn, sp(1e-8f)));
    f32x2 e0 = x0 - d0, e1 = x1 - d1;
    f32x2 eu = sqrt2(fma2(e1, e1, e0 * e0)) * rcp2(xn);
    f32x2 l0 = sp(p.b20), l1 = sp(p.b21);
#pragma unroll
    for (int j = 0; j < 10; ++j) {
        f32x2 a = fma2(enc, sp(p.w1[3*j]),
                  fma2(eu,  sp(p.w1[3*j+1]),
                  fma2(cosv, sp(p.w1[3*j+2]), sp(p.b1[j]))));
        f32x2 e = exp22(a * (2.0f * LOG2E));
        f32x2 h = fma2(sp(-2.0f), rcp2(e + 1.0f), sp(1.0f));
        l0 = fma2(h, sp(p.w2[j]),      l0);
        l1 = fma2(h, sp(p.w2[10 + j]), l1);
    }
    f32x2 m  = max2(l0, l1);
    f32x2 q0 = exp22((l0 - m) * LOG2E);
    f32x2 q1 = exp22((l1 - m) * LOG2E);
    f32x2 inv = rcp2(q0 + q1);
    r.enc = enc; r.d0 = d0; r.d1 = d1; r.eu = eu; r.cosv = cosv;
    r.g0 = q0 * inv; r.g1 = q1 * inv;
    return r;
}

// STREAM-SPLIT GRID: blockIdx in [0, 4*nsb); seg = blockIdx/nsb selects the ONE
// output stream this block writes (0=enc 1=dec 2=z 3=g); each segment re-derives
// its rows from x (L3-resident after the first sweep). Every block's global
// writes are a single contiguous run — same pattern as the 6.5 TB/s fill kernel.
// Wave-local LDS transpose (no barriers), 12 KB/block.

__global__ void __launch_bounds__(256) dagmm_kernel(
    const float* __restrict__ x,
    const float* __restrict__ W_enc,  const float* __restrict__ b_enc,
    const float* __restrict__ W_dec,  const float* __restrict__ b_dec,
    const float* __restrict__ W_est1, const float* __restrict__ b_est1,
    const float* __restrict__ W_est2, const float* __restrict__ b_est2,
    float* __restrict__ out, long long N, int nsb)
{
    __shared__ f32x4 sbuf[4 * 192];

    Params p;
    p.we0 = W_enc[0]; p.we1 = W_enc[1]; p.be = b_enc[0];
    p.wd0 = W_dec[0]; p.wd1 = W_dec[1];
    p.bd0 = b_dec[0]; p.bd1 = b_dec[1];
#pragma unroll
    for (int i = 0; i < 30; ++i) p.w1[i] = W_est1[i];
#pragma unroll
    for (int i = 0; i < 10; ++i) p.b1[i] = b_est1[i];
#pragma unroll
    for (int i = 0; i < 20; ++i) p.w2[i] = W_est2[i];
    p.b20 = b_est2[0]; p.b21 = b_est2[1];

    const int seg = blockIdx.x / nsb;          // block-uniform
    const int b   = blockIdx.x - seg * nsb;

    const int tid = threadIdx.x;
    const int l   = tid & 63;
    const int w   = tid >> 6;
    f32x4* wseg = sbuf + w * 192;

    long long t    = (long long)b * 256 + tid;
    long long row0 = t * 4;

    float* enc_o = out;
    float* dec_o = out + N;
    float* z_o   = out + 3 * N;
    float* g_o   = out + 6 * N;

    const bool fullblock =
        (((long long)b + 1) * 1024 <= N) && ((N & 3LL) == 0);

    if (fullblock) {
        const f32x4* xv = (const f32x4*)x;
        long long wvt = (long long)b * 256 + (w << 6);

        if (seg == 0) {                         // ---- enc ----
            f32x4 xa = xv[2 * t];
            f32x4 xb = xv[2 * t + 1];
            PairOut A = compute_pair(p, (f32x2){xa.x, xa.z}, (f32x2){xa.y, xa.w});
            PairOut B = compute_pair(p, (f32x2){xb.x, xb.z}, (f32x2){xb.y, xb.w});
            f32x4 eV = {A.enc.x, A.enc.y, B.enc.x, B.enc.y};
            __builtin_nontemporal_store(eV, (f32x4*)enc_o + t);
        } else if (seg == 1) {                  // ---- dec ----
            f32x4 xa = xv[2 * t];
            f32x4 xb = xv[2 * t + 1];
            PairOut A = compute_pair(p, (f32x2){xa.x, xa.z}, (f32x2){xa.y, xa.w});
            PairOut B = compute_pair(p, (f32x2){xb.x, xb.z}, (f32x2){xb.y, xb.w});
            f32x4 dV0 = {A.d0.x, A.d1.x, A.d0.y, A.d1.y};
            f32x4 dV1 = {B.d0.x, B.d1.x, B.d0.y, B.d1.y};
            wseg[l]      = dV0;
            wseg[64 + l] = dV1;
            f32x4* dv = (f32x4*)dec_o + 2 * wvt;
#pragma unroll
            for (int k = 0; k < 2; ++k) {
                int j = (k << 6) + l;
                f32x4 a = wseg[((j & 1) << 6) + (j >> 1)];
                __builtin_nontemporal_store(a, dv + j);
            }
        } else if (seg == 2) {                  // ---- z ----
            f32x4 xa = xv[2 * t];
            f32x4 xb = xv[2 * t + 1];
            PairOut A = compute_pair(p, (f32x2){xa.x, xa.z}, (f32x2){xa.y, xa.w});
            PairOut B = compute_pair(p, (f32x2){xb.x, xb.z}, (f32x2){xb.y, xb.w});
            f32x4 zV0 = {A.enc.x, A.eu.x, A.cosv.x, A.enc.y};
            f32x4 zV1 = {A.eu.y, A.cosv.y, B.enc.x, B.eu.x};
            f32x4 zV2 = {B.cosv.x, B.enc.y, B.eu.y, B.cosv.y};
            wseg[l]       = zV0;
            wseg[64 + l]  = zV1;
            wseg[128 + l] = zV2;
            f32x4* zv = (f32x4*)z_o + 3 * wvt;
#pragma unroll
            for (int k = 0; k < 3; ++k) {
                int j = (k << 6) + l;
                int q = j / 3, r = j - 3 * q;
                f32x4 a = wseg[(r << 6) + q];
                __builtin_nontemporal_store(a, zv + j);
            }
        } else {                                // ---- gamma ----
            f32x4 xa = xv[2 * t];
            f32x4 xb = xv[2 * t + 1];
            PairOut A = compute_pair(p, (f32x2){xa.x, xa.z}, (f32x2){xa.y, xa.w});
            PairOut B = compute_pair(p, (f32x2){xb.x, xb.z}, (f32x2){xb.y, xb.w});
            f32x4 gV0 = {A.g0.x, A.g1.x, A.g0.y, A.g1.y};
            f32x4 gV1 = {B.g0.x, B.g1.x, B.g0.y, B.g1.y};
            wseg[l]      = gV0;
            wseg[64 + l] = gV1;
            f32x4* gv = (f32x4*)g_o + 2 * wvt;
#pragma unroll
            for (int k = 0; k < 2; ++k) {
                int j = (k << 6) + l;
                f32x4 a = wseg[((j & 1) << 6) + (j >> 1)];
                __builtin_nontemporal_store(a, gv + j);
            }
        }
    } else {
        // Tail / unaligned fallback: scalar per-row, write only this segment's stream.
        if (row0 >= N) return;
        float o[8];
        long long rend = (row0 + 4 < N) ? (row0 + 4) : N;
        for (long long row = row0; row < rend; ++row) {
            float x0 = x[2*row];
            float x1 = x[2*row + 1];
            compute_row(p, x0, x1, o);
            if (seg == 0) {
                enc_o[row] = o[0];
            } else if (seg == 1) {
                dec_o[2*row] = o[1]; dec_o[2*row+1] = o[2];
            } else if (seg == 2) {
                z_o[3*row] = o[3]; z_o[3*row+1] = o[4]; z_o[3*row+2] = o[5];
            } else {
                g_o[2*row] = o[6]; g_o[2*row+1] = o[7];
            }
        }
    }
}

extern "C" void kernel_launch(void* const* d_in, const int* in_sizes, int n_in,
                              void* d_out, int out_size, void* d_ws, size_t ws_size,
                              hipStream_t stream) {
    long long N = (long long)in_sizes[0] / 2;
    int nsb = (int)((N + 1023) / 1024);   // blocks per segment
    int grid = 4 * nsb;
    dagmm_kernel<<<grid, 256, 0, stream>>>(
        (const float*)d_in[0],
        (const float*)d_in[1], (const float*)d_in[2],
        (const float*)d_in[3], (const float*)d_in[4],
        (const float*)d_in[5], (const float*)d_in[6],
        (const float*)d_in[7], (const float*)d_in[8],
        (float*)d_out, N, nsb);
}

// Round 7
// 319.561 us; speedup vs baseline: 1.0947x; 1.0947x over previous
//
#include <hip/hip_runtime.h>
#include <stdint.h>

typedef float f32x4 __attribute__((ext_vector_type(4)));

#define LOG2E 1.4426950408889634f

__device__ __forceinline__ float rcp_f(float x) { return __builtin_amdgcn_rcpf(x); }
__device__ __forceinline__ float sqrt_f(float x) { return __builtin_amdgcn_sqrtf(x); }
__device__ __forceinline__ float exp2_f(float x) { return __builtin_amdgcn_exp2f(x); }
__device__ __forceinline__ float tanh_fast(float a) {
    // tanh(a) = 1 - 2/(e^{2a}+1); exp2 saturates to 0/inf so tails clamp to -1/+1 exactly
    float e = exp2_f(a * (2.0f * LOG2E));
    return 1.0f - 2.0f * rcp_f(e + 1.0f);
}

struct Params {
    float we0, we1, be, wd0, wd1, bd0, bd1;
    float w1[30], b1[10], w2[20], b20, b21;
};

__device__ __forceinline__ void compute_row(const Params& p, float x0, float x1, float o[8]) {
    float enc = fmaf(x1, p.we1, fmaf(x0, p.we0, p.be));
    float d0  = fmaf(enc, p.wd0, p.bd0);
    float d1  = fmaf(enc, p.wd1, p.bd1);
    float xn  = sqrt_f(fmaf(x1, x1, x0 * x0));
    float dn  = sqrt_f(fmaf(d1, d1, d0 * d0));
    float dot = fmaf(x1, d1, x0 * d0);
    float cosv = dot * rcp_f(fmaxf(xn, 1e-8f) * fmaxf(dn, 1e-8f));
    float e0 = x0 - d0, e1 = x1 - d1;
    float eu = sqrt_f(fmaf(e1, e1, e0 * e0)) * rcp_f(xn);
    float l0 = p.b20, l1 = p.b21;
#pragma unroll
    for (int j = 0; j < 10; ++j) {
        float a = fmaf(enc, p.w1[3*j],
                  fmaf(eu,  p.w1[3*j+1],
                  fmaf(cosv, p.w1[3*j+2], p.b1[j])));
        float h = tanh_fast(a);
        l0 = fmaf(h, p.w2[j],      l0);
        l1 = fmaf(h, p.w2[10 + j], l1);
    }
    float m  = fmaxf(l0, l1);
    float q0 = exp2_f((l0 - m) * LOG2E);
    float q1 = exp2_f((l1 - m) * LOG2E);
    float inv = rcp_f(q0 + q1);
    o[0] = enc; o[1] = d0; o[2] = d1;
    o[3] = enc; o[4] = eu; o[5] = cosv;
    o[6] = q0 * inv; o[7] = q1 * inv;
}

// LDS staging layout (f32x4 units): one buffer, one barrier.
//   dec: [0,    512)   z: [512, 1280)   g: [1280, 1792)   -> 28 KB/block
// Each stream is written COLUMN-SPLIT: component c of thread t at seg + c*256 + t
// (16 B lane stride -> bank-conflict-free). Stream vec j lives at
// seg + (j % C)*256 + j / C  (C = vecs/thread), so the read-back for a
// lane-contiguous global store is a cheap permuted index.
#define SD 0
#define SZ 512
#define SG 1280

__global__ void __launch_bounds__(256) dagmm_kernel(
    const float* __restrict__ x,
    const float* __restrict__ W_enc,  const float* __restrict__ b_enc,
    const float* __restrict__ W_dec,  const float* __restrict__ b_dec,
    const float* __restrict__ W_est1, const float* __restrict__ b_est1,
    const float* __restrict__ W_est2, const float* __restrict__ b_est2,
    float* __restrict__ out, long long N)
{
    __shared__ f32x4 sbuf[1792];  // 28 KB -> 5 blocks/CU (20 waves/CU)

    Params p;
    p.we0 = W_enc[0]; p.we1 = W_enc[1]; p.be = b_enc[0];
    p.wd0 = W_dec[0]; p.wd1 = W_dec[1];
    p.bd0 = b_dec[0]; p.bd1 = b_dec[1];
#pragma unroll
    for (int i = 0; i < 30; ++i) p.w1[i] = W_est1[i];
#pragma unroll
    for (int i = 0; i < 10; ++i) p.b1[i] = b_est1[i];
#pragma unroll
    for (int i = 0; i < 20; ++i) p.w2[i] = W_est2[i];
    p.b20 = b_est2[0]; p.b21 = b_est2[1];

    const int  tid  = threadIdx.x;
    long long  t    = (long long)blockIdx.x * blockDim.x + tid;
    long long  row0 = t * 4;

    float* enc_o = out;
    float* dec_o = out + N;
    float* z_o   = out + 3 * N;
    float* g_o   = out + 6 * N;

    float o[8];
    // Block-uniform predicate: all 1024 rows of this block valid + f32x4-aligned bases.
    const bool fullblock =
        (((long long)blockIdx.x + 1) * 1024 <= N) && ((N & 3LL) == 0);

    if (fullblock) {
        const f32x4* xv = (const f32x4*)x;
        f32x4 xa = xv[2 * t];
        f32x4 xb = xv[2 * t + 1];
        float xr[8] = {xa.x, xa.y, xa.z, xa.w, xb.x, xb.y, xb.z, xb.w};
        union { float s[4];  f32x4 v;    } eU;
        union { float s[8];  f32x4 v[2]; } dU;
        union { float s[12]; f32x4 v[3]; } zU;
        union { float s[8];  f32x4 v[2]; } gU;
#pragma unroll
        for (int r = 0; r < 4; ++r) {
            compute_row(p, xr[2*r], xr[2*r + 1], o);
            eU.s[r]       = o[0];
            dU.s[2*r]     = o[1]; dU.s[2*r+1] = o[2];
            zU.s[3*r]     = o[3]; zU.s[3*r+1] = o[4]; zU.s[3*r+2] = o[5];
            gU.s[2*r]     = o[6]; gU.s[2*r+1] = o[7];
        }

        // enc: already lane-contiguous, store direct.
        __builtin_nontemporal_store(eU.v, (f32x4*)enc_o + t);

        // Stage everything (column-split, conflict-free), ONE barrier.
        sbuf[SD + tid]       = dU.v[0];
        sbuf[SD + 256 + tid] = dU.v[1];
        sbuf[SZ + tid]       = zU.v[0];
        sbuf[SZ + 256 + tid] = zU.v[1];
        sbuf[SZ + 512 + tid] = zU.v[2];
        sbuf[SG + tid]       = gU.v[0];
        sbuf[SG + 256 + tid] = gU.v[1];
        __syncthreads();

        // Read back in stream order, store lane-contiguous (full 64 B lines).
        {
            f32x4* dv = (f32x4*)dec_o + (long long)blockIdx.x * 512;
            f32x4* zv = (f32x4*)z_o   + (long long)blockIdx.x * 768;
            f32x4* gv = (f32x4*)g_o   + (long long)blockIdx.x * 512;
#pragma unroll
            for (int k = 0; k < 2; ++k) {          // dec: C=2
                int j = tid + 256 * k;
                f32x4 a = sbuf[SD + ((j & 1) << 8) + (j >> 1)];
                __builtin_nontemporal_store(a, dv + j);
            }
#pragma unroll
            for (int k = 0; k < 3; ++k) {          // z: C=3
                int j = tid + 256 * k;
                int q = j / 3, r = j - 3 * q;
                f32x4 a = sbuf[SZ + (r << 8) + q];
                __builtin_nontemporal_store(a, zv + j);
            }
#pragma unroll
            for (int k = 0; k < 2; ++k) {          // g: C=2
                int j = tid + 256 * k;
                f32x4 a = sbuf[SG + ((j & 1) << 8) + (j >> 1)];
                __builtin_nontemporal_store(a, gv + j);
            }
        }
    } else {
        // Tail / unaligned fallback: scalar per-row, no barriers (block-uniform branch).
        if (row0 >= N) return;
        long long rend = (row0 + 4 < N) ? (row0 + 4) : N;
        for (long long row = row0; row < rend; ++row) {
            float x0 = x[2*row];
            float x1 = x[2*row + 1];
            compute_row(p, x0, x1, o);
            enc_o[row]     = o[0];
            dec_o[2*row]   = o[1]; dec_o[2*row+1] = o[2];
            z_o[3*row]     = o[3]; z_o[3*row+1]   = o[4]; z_o[3*row+2] = o[5];
            g_o[2*row]     = o[6]; g_o[2*row+1]   = o[7];
        }
    }
}

extern "C" void kernel_launch(void* const* d_in, const int* in_sizes, int n_in,
                              void* d_out, int out_size, void* d_ws, size_t ws_size,
                              hipStream_t stream) {
    long long N = (long long)in_sizes[0] / 2;
    long long nthreads = (N + 3) / 4;
    int block = 256;
    int grid = (int)((nthreads + block - 1) / block);
    dagmm_kernel<<<grid, block, 0, stream>>>(
        (const float*)d_in[0],
        (const float*)d_in[1], (const float*)d_in[2],
        (const float*)d_in[3], (const float*)d_in[4],
        (const float*)d_in[5], (const float*)d_in[6],
        (const float*)d_in[7], (const float*)d_in[8],
        (float*)d_out, N);
}